// Round 8
// baseline (123.051 us; speedup 1.0000x reference)
//
#include <hip/hip_runtime.h>
#include <cstdint>

typedef unsigned long long ull;

#define N_BOX 8192
#define CH 512        // chunk size
#define WPC 8         // words per chunk
#define NCH 16        // chunks

// ---------------- workspace layout ----------------
// TB (distance>=2 transposed col-blocks): 53760 rows * 64 B = 3,440,640 @ 0
// TC (superdiagonal transposed blocks):   15 * 32 KB        =   491,520 @ 3,440,640
// TD (per-chunk diagonal tables):         16 * 32 KB        =   524,288 @ 3,932,160
// boxes4 : 131072 @ 4,456,448
// scores : 32768  @ 4,587,520
// ctrl   : flags on private 128 B lines @ 4,620,288
//          flagK[c] = int c*32 ; vb = int 512 ; flagP[c] = int 1024+c*32
// keptg  : 16 chunks * 16 ull (128 B stride) @ 4,689,920
// pusha  : 16 chunks * 16 ull (128 B stride) @ 4,691,968
#define OFF_TB     0
#define OFF_TC     3440640
#define OFF_TD     3932160
#define OFF_BOXES  4456448
#define OFF_SCORES 4587520
#define OFF_CTRL   4620288
#define OFF_KEPT   4689920
#define OFF_PUSH   4691968

#define CTRL_VB    512    // int index of vb
#define PFLAG      1024   // int index base of push flags (+chunk*32)
#define KSTRIDE    16     // ull stride per chunk in keptg/pusha

// Agent(device)-scope accessors. R7-proven: RELAXED spins (sc1, read MALL,
// no per-poll L2 invalidate — acquire spins were the R6 5us/hop storm);
// release stores order the preceding sc1 data stores.
#define A_LD(p)    __hip_atomic_load((p), __ATOMIC_RELAXED, __HIP_MEMORY_SCOPE_AGENT)
#define A_ST(p,v)  __hip_atomic_store((p), (v), __ATOMIC_RELAXED, __HIP_MEMORY_SCOPE_AGENT)
#define A_STR(p,v) __hip_atomic_store((p), (v), __ATOMIC_RELEASE, __HIP_MEMORY_SCOPE_AGENT)

// TB rows for source chunk c' cover j >= CH*(c'+2): 7168-512c' rows (c'=0..13)
__device__ __forceinline__ int rows_before2(int c) {
    return 7424 * c - 256 * c * c;   // sum_{c'<c} (7168 - 512c')
}

__device__ __forceinline__ ull make_key(float s, int idx) {
    // positive floats: bit pattern is order-preserving. Reversed index in the
    // low 13 bits reproduces stable argsort(-conf): equal conf -> lower index first.
    return (((ull)__float_as_uint(s)) << 13) | (ull)(8191 - idx);
}

__device__ __forceinline__ float box_area(float4 b) {
    return __fmul_rn(__fsub_rn(b.z, b.x), __fsub_rn(b.w, b.y));
}

// exact replica of reference IoU rounding (_rn ops block FMA contraction); symmetric.
__device__ __forceinline__ bool iou_gt_half(float4 a, float aarea, float4 b, float barea) {
    float ix1 = fmaxf(a.x, b.x);
    float iy1 = fmaxf(a.y, b.y);
    float ix2 = fminf(a.z, b.z);
    float iy2 = fminf(a.w, b.w);
    float iw = fmaxf(__fsub_rn(ix2, ix1), 0.0f);
    float ih = fmaxf(__fsub_rn(iy2, iy1), 0.0f);
    float inter = __fmul_rn(iw, ih);
    float uni = __fsub_rn(__fadd_rn(aarea, barea), inter);
    float iou = __fdiv_rn(inter, fmaxf(uni, 1e-9f));
    return iou > 0.5f;
}

// kA: fused max + rank + scatter, REGISTER-BLOCKED rank (round-8 redesign).
// Old kA streamed 2 MB of LDS per block (256 thr x 1024 ds_read_b64) ->
// ~6.8us LDS-throughput floor. New: thread t keeps ITS 32 keys (indices
// r*256+t) in registers; for each of the block's 32 i-keys (read once via
// LDS broadcast) all threads compare their reg keys -> per-wave shfl reduce
// -> LDS atomicAdd. Inner loop has ZERO memory accesses (R2 lesson n/a).
// Rank semantics identical: rank[i] = #{j : key_j > key_i}.
__global__ __launch_bounds__(256) void kA_rank_scatter(const float* __restrict__ in,
                                                       float4* __restrict__ boxes4,
                                                       float* __restrict__ scores,
                                                       int* __restrict__ ctrl) {
    __shared__ ull ikey[32];
    __shared__ int rank32[32];
    __shared__ float wm[4];
    __shared__ int wv[4];
    int t = threadIdx.x;
    int bx = blockIdx.x;
    if (t < 32) rank32[t] = 0;

    // ---- stage confs into regs; block-local max (== global max, exact) ----
    float cf[32];
    float m = 0.0f;                    // conf >= 0 so 0-seed is safe
    #pragma unroll
    for (int r = 0; r < 32; ++r) {
        cf[r] = in[(r * 256 + t) * 5 + 4];
        m = fmaxf(m, cf[r]);
    }
    for (int off = 32; off; off >>= 1) m = fmaxf(m, __shfl_down(m, off));
    if ((t & 63) == 0) wm[t >> 6] = m;
    __syncthreads();
    float maxc = fmaxf(fmaxf(wm[0], wm[1]), fmaxf(wm[2], wm[3]));

    // ---- this thread's 32 keys, in registers ----
    ull kk[32];
    #pragma unroll
    for (int r = 0; r < 32; ++r)
        kk[r] = make_key(__fdiv_rn(cf[r], maxc), r * 256 + t);

    // ---- publish the block's 32 i-keys (owner threads) ----
    int il = t - ((bx & 7) * 32);      // i = bx*32+il held by thread (bx&7)*32+il, r = bx>>3
    if (il >= 0 && il < 32) ikey[il] = kk[bx >> 3];
    __syncthreads();

    // ---- count: 32 i's x 32 reg-keys, all-VALU inner loop ----
    for (int ii = 0; ii < 32; ++ii) {
        ull ik = ikey[ii];             // LDS broadcast, once per ii
        int cnt = 0;
        #pragma unroll
        for (int r = 0; r < 32; ++r) cnt += (kk[r] > ik) ? 1 : 0;
        for (int off = 32; off; off >>= 1) cnt += __shfl_down(cnt, off);
        if ((t & 63) == 0) atomicAdd(&rank32[ii], cnt);
    }
    __syncthreads();

    // ---- scatter: thread t<32 owns box i = bx*32+t ----
    if (t < 32) {
        int i = bx * 32 + t;
        int r = rank32[t];             // descending-sort position
        float cx = in[i * 5 + 0];
        float cy = in[i * 5 + 1];
        float w  = in[i * 5 + 2];
        float h  = in[i * 5 + 3];
        float s  = __fdiv_rn(in[i * 5 + 4], maxc);
        float4 b;
        b.x = __fsub_rn(cx, __fmul_rn(w, 0.5f));
        b.y = __fsub_rn(cy, __fmul_rn(h, 0.5f));
        b.z = __fadd_rn(cx, __fmul_rn(w, 0.5f));
        b.w = __fadd_rn(cy, __fmul_rn(h, 0.5f));
        boxes4[r] = b;
        scores[r] = s;
    }

    // ---- block 0: vb + zero chain flags (poisoned workspace) ----
    if (bx == 0) {
        const ull kthr = ((ull)0x3F000000u) << 13;   // s >= 0.5 boundary
        int cv = 0;
        #pragma unroll
        for (int r = 0; r < 32; ++r) cv += (kk[r] >= kthr) ? 1 : 0;
        for (int off = 32; off; off >>= 1) cv += __shfl_down(cv, off);
        if ((t & 63) == 0) wv[t >> 6] = cv;
        if (t < NCH) ctrl[t * 32] = 0;               // flagK
        if (t < NCH) ctrl[PFLAG + t * 32] = 0;       // flagP
        __syncthreads();
        if (t == 0) ctrl[CTRL_VB] = wv[0] + wv[1] + wv[2] + wv[3];
    }
}

// K4: build suppression bit tables (R7-verbatim, passed). 2176 blocks / 8 per
// CU TLP; IoU inner loop bank-STAGGERED (kk=(k+w)&63, bit-identical output).
__global__ __launch_bounds__(256) void k4_build(const float4* __restrict__ boxes4,
                                                const float* __restrict__ scores,
                                                ull* __restrict__ TB,
                                                ull* __restrict__ TC,
                                                ull* __restrict__ TD) {
    __shared__ float4 sb[CH];
    __shared__ float sa[CH];
    int bid = blockIdx.x;
    int t = threadIdx.x;
    int c;
    int mode;   // 0=TB, 1=TC, 2=TD
    int j0;     // TB: global j tile start; TC/TD: local jl tile start
    if (bid >= 1920) {
        mode = 2;
        int d = bid - 1920;
        c = d >> 4;
        j0 = (d & 15) * 32;
    } else if (bid >= 1680) {
        mode = 1;
        int d = bid - 1680;
        c = d >> 4;          // 0..14
        j0 = (d & 15) * 32;
    } else {
        mode = 0;
        c = 0;
        int rem = bid;
        while (rem >= 224 - 16 * c) { rem -= 224 - 16 * c; ++c; }
        j0 = CH * (c + 2) + rem * 32;
    }
    if (scores[c * CH] < 0.5f) return;               // source chunk never a suppressor
    if (mode == 0 && scores[j0] < 0.5f) return;      // j-tile never alive (desc scores)

    for (int i = t; i < CH; i += 256) {
        float4 b = boxes4[c * CH + i];
        sb[i] = b;
        sa[i] = box_area(b);
    }
    __syncthreads();

    int w = t & 7;
    int r = t >> 3;          // 0..31 local row
    int jl = j0 + r;         // mode 2/1: local row; mode 0: global j
    float4 me;
    float ma;
    int lim = 64;
    if (mode == 2) {
        me = sb[jl];
        ma = sa[jl];
        int wj = jl >> 6;
        lim = (w < wj) ? 64 : ((w == wj) ? (jl & 63) : 0);
    } else if (mode == 1) {
        me = boxes4[CH * (c + 1) + jl];
        ma = box_area(me);
    } else {
        me = boxes4[jl];
        ma = box_area(me);
    }
    ull bits = 0;
    #pragma unroll 8
    for (int k = 0; k < 64; ++k) {
        int kk = (k + w) & 63;         // bank stagger, bit-identical output
        if (kk < lim &&
            iou_gt_half(sb[w * 64 + kk], sa[w * 64 + kk], me, ma))
            bits |= 1ull << kk;
    }
    if (mode == 2)      TD[c * 4096 + w * 512 + jl] = bits;
    else if (mode == 1) TC[c * 4096 + w * 512 + jl] = bits;
    else TB[(size_t)(rows_before2(c) + (jl - CH * (c + 2))) * WPC + w] = bits;
}

// wave-0 chunk scan: TD fixpoint over amask, then publish kept words + flag.
// Verbatim R3-R7 logic, factored for dual use.
__device__ __forceinline__ void scan_chunk(const ull* T, unsigned* am,
                                           ull* keptrow, int* flag, int lane) {
    ull alive[WPC];
    #pragma unroll
    for (int w = 0; w < WPC; ++w)
        alive[w] = (ull)am[2 * w] | ((ull)am[2 * w + 1] << 32);
    #pragma unroll
    for (int w = 0; w < WPC; ++w) {
        ull word = alive[w];
        if (!word) continue;
        ull Tc[WPC];
        #pragma unroll
        for (int j = 0; j < WPC; ++j)
            if (j >= w) Tc[j] = T[w * 512 + j * 64 + lane];
        ull td = Tc[w];
        ull a2 = word, kept = 0;
        while (a2 & ~kept) {
            bool al = (a2 >> lane) & 1;
            bool kp = (kept >> lane) & 1;
            ull nk = __ballot(al && !kp && ((td & a2) == 0));
            ull nd = __ballot(al && !kp && ((td & kept) != 0));
            kept |= nk;
            a2 &= ~nd;
        }
        alive[w] = kept;
        #pragma unroll
        for (int j = 0; j < WPC; ++j) {
            if (j <= w) continue;
            if (!alive[j]) continue;
            alive[j] &= ~__ballot((Tc[j] & kept) != 0);
        }
    }
    if (lane == 0) {
        #pragma unroll
        for (int w = 0; w < WPC; ++w) {
            A_ST(&keptrow[w], alive[w]);
            am[2 * w]     = (unsigned)alive[w];
            am[2 * w + 1] = (unsigned)(alive[w] >> 32);
        }
        A_STR(flag, 1);
    }
}

// K5: PAIRED-chunk chain NMS (round-8). 8 blocks; block c owns chunks
// a=2c, b=2c+1. The a->b handoff is in-block (syncthreads) — halves the
// cross-XCD MALL hops (8 -> 4). LDS holds BOTH TD tables (64 KB); the two
// TC applies (internal a->b, push b->2c+2) use TCg values PREFETCHED into
// registers before the flag waits, so they are pure-VALU on the chain path.
// Handoff protocol is R7-verbatim (relaxed spins, release publishes).
__global__ __launch_bounds__(1024) void k5_nms(const float4* __restrict__ boxes4,
                                               const float* __restrict__ scores,
                                               const ull* __restrict__ TBg,
                                               const ull* __restrict__ TCg,
                                               const ull* __restrict__ TDg,
                                               ull* __restrict__ keptg,
                                               ull* __restrict__ pusha,
                                               int* __restrict__ ctrl,
                                               float* __restrict__ out) {
    __shared__ ull TDs[8192];          // 64 KB: TD[a] @0, TD[b] @4096
    __shared__ ull kwsh[WPC];
    __shared__ ull darr[WPC];
    __shared__ unsigned amask[32];     // chunk a bits 0..511, chunk b bits 512..1023
    const int c = blockIdx.x;
    const int t = threadIdx.x;
    const int lane = t & 63;
    const int wave = t >> 6;
    const int a = 2 * c;
    const int b = a + 1;
    int vb = ctrl[CTRL_VB];
    int nchv = (vb + CH - 1) / CH;
    bool aLive = (a < nchv);
    bool bLive = (b < nchv);

    if (aLive) {
        // ---- stage TD[a] (+TD[b]); init alive masks ----
        {
            const ulonglong2* src = (const ulonglong2*)(TDg + (size_t)a * 4096);
            ulonglong2* dst = (ulonglong2*)TDs;
            #pragma unroll
            for (int i2 = t; i2 < 2048; i2 += 1024) dst[i2] = src[i2];
        }
        if (bLive) {
            const ulonglong2* src = (const ulonglong2*)(TDg + (size_t)b * 4096);
            ulonglong2* dst = (ulonglong2*)(TDs + 4096);
            #pragma unroll
            for (int i2 = t; i2 < 2048; i2 += 1024) dst[i2] = src[i2];
        }
        if (t < 32) {
            int n = vb - (a * 16 + t) * 32;
            amask[t] = (n >= 32) ? 0xffffffffu : ((n <= 0) ? 0u : ((1u << n) - 1u));
        }

        // ---- prefetch TC columns into registers (hidden under waits) ----
        ull tca[WPC], tcb[WPC];
        if (bLive && wave < WPC) {
            const ull* p = TCg + (size_t)a * 4096 + wave * 64 + lane;
            #pragma unroll
            for (int w = 0; w < WPC; ++w) tca[w] = p[w * 512];
        }
        if (b + 1 < nchv && wave < WPC) {
            const ull* p = TCg + (size_t)b * 4096 + wave * 64 + lane;
            #pragma unroll
            for (int w = 0; w < WPC; ++w) tcb[w] = p[w * 512];
        }
        __syncthreads();

        // ---- TB applies: kept[cp] -> chunk a (cp<=a-2) and b (cp<=a-1) ----
        int cpmax = bLive ? (a - 1) : (a - 2);
        if (cpmax > 13) cpmax = 13;
        for (int cp = 0; cp <= cpmax; ++cp) {
            if (wave == 0) {
                if (lane == 0) { while (A_LD(&ctrl[cp * 32]) != 1) {} }
                if (lane < WPC) kwsh[lane] = A_LD(&keptg[cp * KSTRIDE + lane]);
            }
            __syncthreads();
            ull anyk = kwsh[0] | kwsh[1] | kwsh[2] | kwsh[3] |
                       kwsh[4] | kwsh[5] | kwsh[6] | kwsh[7];
            if (anyk) {
                int jl = t & 511;
                int ch = (t < 512) ? a : b;
                bool act = (t < 512) ? (cp <= a - 2) : bLive;
                if (act && ((amask[t >> 5] >> (t & 31)) & 1u)) {
                    int j = ch * CH + jl;
                    const ull* row = TBg +
                        (size_t)(rows_before2(cp) + (j - CH * (cp + 2))) * WPC;
                    ull x = 0;
                    #pragma unroll
                    for (int q = 0; q < WPC; ++q) x |= row[q] & kwsh[q];
                    if (x) atomicAnd(&amask[t >> 5], ~(1u << (t & 31)));
                }
            }
            __syncthreads();
        }

        // ---- pushed TC suppression -> chunk a (from block c-1) ----
        if (a > 0) {
            if (wave == 0) {
                if (lane == 0) { while (A_LD(&ctrl[PFLAG + a * 32]) != 1) {} }
                if (lane < WPC) kwsh[lane] = A_LD(&pusha[a * KSTRIDE + lane]);
            }
            __syncthreads();
            if (t < WPC) {
                ull s = kwsh[t];
                amask[2 * t]     &= ~(unsigned)s;
                amask[2 * t + 1] &= ~(unsigned)(s >> 32);
            }
            __syncthreads();
        }

        // ---- scan chunk a; publish kept[a] + flagK[a] ----
        if (wave == 0)
            scan_chunk(TDs, amask, &keptg[a * KSTRIDE], &ctrl[a * 32], lane);
        __syncthreads();

        if (bLive) {
            // ---- internal TC apply: kept[a] -> chunk b (registers, no loads) ----
            if (wave < WPC) {
                bool dead = false;
                #pragma unroll
                for (int w = 0; w < WPC; ++w) {
                    ull kw = (ull)amask[2 * w] | ((ull)amask[2 * w + 1] << 32);
                    if (kw) dead |= (tca[w] & kw) != 0ull;
                }
                ull d = __ballot(dead);
                if (lane == 0 && d) {
                    amask[16 + 2 * wave]     &= ~(unsigned)d;
                    amask[16 + 2 * wave + 1] &= ~(unsigned)(d >> 32);
                }
            }
            __syncthreads();

            // ---- scan chunk b; publish kept[b] + flagK[b] ----
            if (wave == 0)
                scan_chunk(TDs + 4096, amask + 16, &keptg[b * KSTRIDE],
                           &ctrl[b * 32], lane);
            __syncthreads();

            // ---- push: TC apply for chunk b+1 (registers), publish ----
            if (b + 1 < nchv) {
                if (wave < WPC) {
                    bool dead = false;
                    #pragma unroll
                    for (int w = 0; w < WPC; ++w) {
                        ull kw = (ull)amask[16 + 2 * w] | ((ull)amask[16 + 2 * w + 1] << 32);
                        if (kw) dead |= (tcb[w] & kw) != 0ull;
                    }
                    ull d = __ballot(dead);
                    if (lane == 0) darr[wave] = d;
                }
                __syncthreads();
                if (t == 0) {
                    #pragma unroll
                    for (int w = 0; w < WPC; ++w)
                        A_ST(&pusha[(b + 1) * KSTRIDE + w], darr[w]);
                    A_STR(&ctrl[PFLAG + (b + 1) * 32], 1);
                }
            }
        }
        __syncthreads();
    } else {
        if (t < 32) amask[t] = 0u;
        __syncthreads();
    }

    // ---- epilogue: write the pair's 1024 output rows ----
    {
        int j = a * CH + t;            // t = 0..1023 spans chunks a and b
        bool kept = (amask[t >> 5] >> (t & 31)) & 1u;
        float4 bx = boxes4[j];
        float s = scores[j];
        out[j * 5 + 0] = kept ? bx.x : 0.0f;
        out[j * 5 + 1] = kept ? bx.y : 0.0f;
        out[j * 5 + 2] = kept ? bx.z : 0.0f;
        out[j * 5 + 3] = kept ? bx.w : 0.0f;
        out[j * 5 + 4] = kept ? s    : 0.0f;
    }
}

extern "C" void kernel_launch(void* const* d_in, const int* in_sizes, int n_in,
                              void* d_out, int out_size, void* d_ws, size_t ws_size,
                              hipStream_t stream) {
    const float* in = (const float*)d_in[0];
    char* ws = (char*)d_ws;
    ull* TB        = (ull*)(ws + OFF_TB);
    ull* TC        = (ull*)(ws + OFF_TC);
    ull* TD        = (ull*)(ws + OFF_TD);
    float4* boxes4 = (float4*)(ws + OFF_BOXES);
    float* scores  = (float*)(ws + OFF_SCORES);
    int* ctrl      = (int*)(ws + OFF_CTRL);
    ull* keptg     = (ull*)(ws + OFF_KEPT);
    ull* pusha     = (ull*)(ws + OFF_PUSH);
    float* out     = (float*)d_out;

    kA_rank_scatter<<<256, 256, 0, stream>>>(in, boxes4, scores, ctrl);
    k4_build<<<2176, 256, 0, stream>>>(boxes4, scores, TB, TC, TD);
    k5_nms<<<8, 1024, 0, stream>>>(boxes4, scores, TB, TC, TD, keptg, pusha, ctrl, out);
}